// Round 15
// baseline (111.923 us; speedup 1.0000x reference)
//
#include <hip/hip_runtime.h>

#define SEQ    2048
#define NBATCH 2
#define NHEAD  16
#define HD     64
#define MD     1024
#define TOK    (SEQ * NBATCH)   // 4096
#define WN8    (MD * MD / 8)    // 131072 = 2^17

typedef __attribute__((ext_vector_type(4)))  float f32x4;
typedef __attribute__((ext_vector_type(16))) float f32x16;
typedef __attribute__((ext_vector_type(8)))  short bf16x8;
typedef __attribute__((ext_vector_type(8)))  unsigned short u16x8;

__device__ __forceinline__ unsigned short f2bf(float f) {
  union { float f; unsigned int u; } x; x.f = f;
  unsigned int u = x.u + 0x7fffu + ((x.u >> 16) & 1u);   // RNE; inputs are finite
  return (unsigned short)(u >> 16);
}

// v_cvt_pk_bf16_f32: D[15:0]=bf16(lo), D[31:16]=bf16(hi)  (no builtin on gfx950)
__device__ __forceinline__ unsigned cvtpk(float lo, float hi) {
  unsigned r;
  asm("v_cvt_pk_bf16_f32 %0, %1, %2" : "=v"(r) : "v"(lo), "v"(hi));
  return r;
}
// v_permlane32_swap_b32: a' = (a_lo | b_lo), b' = (a_hi | b_hi)
__device__ __forceinline__ void plswap(unsigned &a, unsigned &b) {
  asm volatile("v_permlane32_swap_b32 %0, %1" : "+v"(a), "+v"(b));
}

__device__ __forceinline__ void gload_lds16(const void* g, void* l) {
  typedef const __attribute__((address_space(1))) unsigned int* gp_t;
  typedef __attribute__((address_space(3))) unsigned int* lp_t;
  __builtin_amdgcn_global_load_lds((gp_t)g, (lp_t)l, 16, 0, 0);
}

// -------- fp32 -> bf16 convert, weights only (X is fused into gemm_qkv) ---
__global__ __launch_bounds__(256) void cvt_w(
    const float* __restrict__ wq, const float* __restrict__ wk,
    const float* __restrict__ wv, const float* __restrict__ wo,
    unsigned short* __restrict__ owq, unsigned short* __restrict__ owk,
    unsigned short* __restrict__ owv, unsigned short* __restrict__ owo) {
  const int i = blockIdx.x * 256 + threadIdx.x;
  const int s = i >> 17;           // WN8 = 2^17; boundaries 256-aligned
  const int r = i & (WN8 - 1);
  const float* src = s == 0 ? wq : (s == 1 ? wk : (s == 2 ? wv : wo));
  unsigned short* dst = s == 0 ? owq : (s == 1 ? owk : (s == 2 ? owv : owo));
  const float4* p = (const float4*)src + (size_t)r * 2;
  float4 a = p[0];
  float4 b = p[1];
  u16x8 o;
  o[0] = f2bf(a.x); o[1] = f2bf(a.y); o[2] = f2bf(a.z); o[3] = f2bf(a.w);
  o[4] = f2bf(b.x); o[5] = f2bf(b.y); o[6] = f2bf(b.z); o[7] = f2bf(b.w);
  *((u16x8*)dst + r) = o;
}

// ---- fused cvt+QKV projection, R15: 1024 threads / 16 waves (4Mx4N of
// 32x32). Staging split by wave role: waves 0-7 = X-side (fp32->bf16
// reg-stage, depth-2 two-reg-set pipeline, 2 float4/tile/thread), waves
// 8-15 = W-side (1 gload_lds/tile/thread). Per-role counted vmcnt:
// X steady vmcnt(2)+lgkmcnt(0), W steady vmcnt(1). T1 XCD swizzle.
__global__ __launch_bounds__(1024) void gemm_qkv(
    const float* __restrict__ Xq, const float* __restrict__ Xk,
    const float* __restrict__ Xv, const unsigned short* __restrict__ Wq,
    const unsigned short* __restrict__ Wk, const unsigned short* __restrict__ Wv,
    const float* __restrict__ bq, const float* __restrict__ bk, const float* __restrict__ bv,
    unsigned short* __restrict__ Qo, unsigned short* __restrict__ Ko,
    unsigned short* __restrict__ Vo, float qscale) {
  __shared__ unsigned short sA[3][128 * 32];   // M-side
  __shared__ unsigned short sB[3][128 * 32];   // N-side
  const int tid  = threadIdx.x;
  const int lane = tid & 63;
  const int wave = tid >> 6;            // 0..15
  const int wm   = (wave >> 2) << 5;    // 4 M-waves x 32
  const int wn   = (wave & 3) << 5;     // 4 N-waves x 32
  const int l15  = lane & 15;
  const int g    = lane >> 4;
  const bool isX = tid < 512;           // wave-uniform role split

  // T1 swizzle decode: flat = x + 8y + 256z; f(x,gr)=64*(gr>>3)+8x+(gr&7),
  // gr = y + 32z. All 8 x-blocks of a group share flat%8 -> one XCD.
  const int flat = blockIdx.x + (blockIdx.y << 3) + (blockIdx.z << 8);
  const int nx   = (flat & 63) >> 3;               // N-tile 0..7
  const int gr   = ((flat >> 6) << 3) + (flat & 7);// group 0..95
  const int ny   = gr & 31;                        // M-tile 0..31
  const int z    = gr >> 5;                        // 0..2

  const float* Xf; const unsigned short* Wb; const float* bias;
  if (z == 0)      { Xf = Xq; Wb = Wq; bias = bq; }
  else if (z == 1) { Xf = Xk; Wb = Wk; bias = bk; }
  else             { Xf = Xv; Wb = Wv; bias = bv; }
  int bM, bN;
  if (z < 2) { bM = ny << 7; bN = nx << 7; }
  else       { bM = nx << 7; bN = ny << 7; }
  const int bX = (z < 2) ? bM : bN;     // X (token) side base row
  const int bW = (z < 2) ? bN : bM;     // W (channel) side base row
  unsigned short* sX3 = (z < 2) ? &sA[0][0] : &sB[0][0];
  unsigned short* sW3 = (z < 2) ? &sB[0][0] : &sA[0][0];

  f32x4 acc[2][2];
#pragma unroll
  for (int a_ = 0; a_ < 2; ++a_)
#pragma unroll
    for (int b_ = 0; b_ < 2; ++b_)
      acc[a_][b_] = f32x4{0.f, 0.f, 0.f, 0.f};

  // staging geometry: ct in [0,512) covers one 8KB bf16 tile in 16B chunks
  const int ct = tid & 511;
  const int r = ct >> 2, cc = ct & 3;
  const float* xsrc = Xf + (size_t)(bX + r) * MD + cc * 8;
  const unsigned short* wsrc = Wb + (size_t)(bW + r) * MD + cc * 8;

  // two named X reg sets (static indexing; rule #20) — X-waves only
  float4 ra0, rb0, ra1, rb1;
  auto xissue0 = [&](int kt) {
    ra0 = *(const float4*)(xsrc + (kt << 5));
    rb0 = *(const float4*)(xsrc + (kt << 5) + 4);
  };
  auto xissue1 = [&](int kt) {
    ra1 = *(const float4*)(xsrc + (kt << 5));
    rb1 = *(const float4*)(xsrc + (kt << 5) + 4);
  };
  auto xwrite0 = [&](int c) {
    union { unsigned u[4]; bf16x8 v; } w;
    w.u[0] = cvtpk(ra0.x, ra0.y); w.u[1] = cvtpk(ra0.z, ra0.w);
    w.u[2] = cvtpk(rb0.x, rb0.y); w.u[3] = cvtpk(rb0.z, rb0.w);
    *(bf16x8*)(sX3 + c * 4096 + ct * 8) = w.v;
  };
  auto xwrite1 = [&](int c) {
    union { unsigned u[4]; bf16x8 v; } w;
    w.u[0] = cvtpk(ra1.x, ra1.y); w.u[1] = cvtpk(ra1.z, ra1.w);
    w.u[2] = cvtpk(rb1.x, rb1.y); w.u[3] = cvtpk(rb1.z, rb1.w);
    *(bf16x8*)(sX3 + c * 4096 + ct * 8) = w.v;
  };
  auto wissue = [&](int c, int kt) {
    gload_lds16(wsrc + (kt << 5), (char*)(sW3 + c * 4096) + ct * 16);
  };

  auto mfma_step = [&](int c) {
    bf16x8 af[2], bfr[2];
#pragma unroll
    for (int f = 0; f < 2; ++f)
      af[f] = *(const bf16x8*)&sA[c][(wm + f * 16 + l15) * 32 + g * 8];
#pragma unroll
    for (int f = 0; f < 2; ++f)
      bfr[f] = *(const bf16x8*)&sB[c][(wn + f * 16 + l15) * 32 + g * 8];
#pragma unroll
    for (int mf = 0; mf < 2; ++mf)
#pragma unroll
      for (int nf = 0; nf < 2; ++nf)
        acc[mf][nf] = __builtin_amdgcn_mfma_f32_16x16x32_bf16(af[mf], bfr[nf], acc[mf][nf], 0, 0, 0);
  };

  const int nk = MD >> 5;               // 32 (even)
  // per-role end-of-epoch wait: retire everything issued BEFORE this
  // epoch, leave this epoch's issues in flight.
  auto endwait = [&](int e) {
    if (isX) {
      if (e + 4 < nk) asm volatile("s_waitcnt vmcnt(2)" ::: "memory");
      else            asm volatile("s_waitcnt vmcnt(0)" ::: "memory");
      asm volatile("s_waitcnt lgkmcnt(0)" ::: "memory");   // ds_write visible
    } else {
      if (e + 2 < nk) asm volatile("s_waitcnt vmcnt(1)" ::: "memory");
      else            asm volatile("s_waitcnt vmcnt(0)" ::: "memory");
    }
    __builtin_amdgcn_s_barrier();
  };

  // prologue
  if (isX) {
    xissue0(0);                         // 2 loads
    xissue1(1);                         // 2
    asm volatile("s_waitcnt vmcnt(2)" ::: "memory");   // X(0) landed
    xwrite0(0);
    asm volatile("s_waitcnt vmcnt(0)" ::: "memory");   // X(1) landed
    xwrite1(1);
    xissue0(2);
    xissue1(3);
    asm volatile("s_waitcnt lgkmcnt(0)" ::: "memory");
  } else {
    wissue(0, 0);
    wissue(1, 1);
    asm volatile("s_waitcnt vmcnt(0)" ::: "memory");   // W(0),W(1) landed
  }
  __builtin_amdgcn_s_barrier();

  for (int kt = 0; kt < nk; kt += 2) {
    // even epoch kt: X set0 holds X(kt+2)
    if (isX) {
      if (kt + 2 < nk) xwrite0((kt + 2) % 3);
      if (kt + 4 < nk) xissue0(kt + 4);
    } else {
      if (kt + 2 < nk) wissue((kt + 2) % 3, kt + 2);
    }
    mfma_step(kt % 3);
    endwait(kt);                         // kt <= nk-2: always waits+barriers
    // odd epoch kt+1: X set1 holds X(kt+3)
    if (isX) {
      if (kt + 3 < nk) xwrite1((kt + 3) % 3);
      if (kt + 5 < nk) xissue1(kt + 5);
    } else {
      if (kt + 3 < nk) wissue((kt + 3) % 3, kt + 3);
    }
    mfma_step((kt + 1) % 3);
    if (kt + 2 < nk) endwait(kt + 1);    // skip after last epoch
  }

  if (z < 2) {
    unsigned short* O = (z == 0) ? Qo : Ko;
    const float scale = (z == 0) ? qscale : 1.0f;
#pragma unroll
    for (int nf = 0; nf < 2; ++nf) {
      const int cch = bN + wn + nf * 16 + l15;
      const float bb = bias[cch];
      const int h = cch >> 6, d = cch & 63;
#pragma unroll
      for (int mf = 0; mf < 2; ++mf)
#pragma unroll
        for (int i = 0; i < 4; ++i) {
          const int t = bM + wm + mf * 16 + (g << 2) + i;
          const int b = t & 1, s = t >> 1;
          O[((((b << 4) + h) * SEQ + s) << 6) + d] = f2bf((acc[mf][nf][i] + bb) * scale);
        }
    }
  } else {
#pragma unroll
    for (int mf = 0; mf < 2; ++mf)
#pragma unroll
      for (int i = 0; i < 4; ++i) {
        const int rch = bM + wm + mf * 16 + (g << 2) + i;
        const float bb = bias[rch];
        const int h = rch >> 6, d = rch & 63;
#pragma unroll
        for (int nf = 0; nf < 2; ++nf) {
          const int t = bN + wn + nf * 16 + l15;
          const int b = t & 1, s = t >> 1;
          Vo[((((b << 4) + h) << 6) + d) * SEQ + s] = f2bf(acc[mf][nf][i] + bb);
        }
      }
  }
}

// -------- O projection: fp32 out, 16 waves, counted-vmcnt + T1 swizzle ----
// (R14, verified)
__global__ __launch_bounds__(1024) void gemm_oproj(const unsigned short* __restrict__ A,
                                                   const unsigned short* __restrict__ B,
                                                   const float* __restrict__ bias,
                                                   float* __restrict__ O) {
  __shared__ unsigned short sA[3][128 * 32];
  __shared__ unsigned short sB[3][128 * 32];
  const int tid  = threadIdx.x;
  const int lane = tid & 63;
  const int wave = tid >> 6;            // 0..15
  const int wm   = (wave >> 2) << 5;    // 4 M-waves x 32
  const int wn   = (wave & 3) << 5;     // 4 N-waves x 32
  const int l15  = lane & 15;
  const int g    = lane >> 4;

  // T1 swizzle: 8 N-blocks sharing an A panel -> same XCD (gr = y, 0..31)
  const int flat = blockIdx.x + (blockIdx.y << 3);   // 0..255
  const int nx   = (flat & 63) >> 3;
  const int gr   = ((flat >> 6) << 3) + (flat & 7);  // 0..31
  const int bM   = gr << 7;
  const int bN   = nx << 7;

  f32x4 acc[2][2];
#pragma unroll
  for (int a_ = 0; a_ < 2; ++a_)
#pragma unroll
    for (int b_ = 0; b_ < 2; ++b_)
      acc[a_][b_] = f32x4{0.f, 0.f, 0.f, 0.f};

  const int ct = tid & 511;
  const int r = ct >> 2, cc = ct & 3;
  const unsigned short* srow = (tid < 512)
      ? A + (size_t)(bM + r) * MD + cc * 8
      : B + (size_t)(bN + r) * MD + cc * 8;
  unsigned short* sdst3 = (tid < 512) ? &sA[0][0] : &sB[0][0];
  auto stage = [&](int c, int kt) {
    gload_lds16(srow + (kt << 5), (char*)(sdst3 + c * 4096) + ct * 16);
  };

  const int nk = MD >> 5;
  stage(0, 0);
  stage(1, 1);
  asm volatile("s_waitcnt vmcnt(1)" ::: "memory");   // tile 0 landed
  __builtin_amdgcn_s_barrier();

  int cur = 0;
  for (int kt = 0; kt < nk; ++kt) {
    if (kt + 2 < nk) stage(cur == 0 ? 2 : cur - 1, kt + 2);
    bf16x8 af[2], bfr[2];
#pragma unroll
    for (int f = 0; f < 2; ++f)
      af[f] = *(const bf16x8*)&sA[cur][(wm + f * 16 + l15) * 32 + g * 8];
#pragma unroll
    for (int f = 0; f < 2; ++f)
      bfr[f] = *(const bf16x8*)&sB[cur][(wn + f * 16 + l15) * 32 + g * 8];
#pragma unroll
    for (int mf = 0; mf < 2; ++mf)
#pragma unroll
      for (int nf = 0; nf < 2; ++nf)
        acc[mf][nf] = __builtin_amdgcn_mfma_f32_16x16x32_bf16(af[mf], bfr[nf], acc[mf][nf], 0, 0, 0);
    if (kt + 2 < nk)
      asm volatile("s_waitcnt vmcnt(1)" ::: "memory");   // tile kt+1 landed
    else if (kt + 1 < nk)
      asm volatile("s_waitcnt vmcnt(0)" ::: "memory");
    if (kt + 1 < nk) __builtin_amdgcn_s_barrier();
    cur = (cur == 2) ? 0 : cur + 1;
  }

#pragma unroll
  for (int nf = 0; nf < 2; ++nf) {
    const int cch = bN + wn + nf * 16 + l15;
    const float bb = bias[cch];
#pragma unroll
    for (int mf = 0; mf < 2; ++mf)
#pragma unroll
      for (int i = 0; i < 4; ++i) {
        const int t = bM + wm + mf * 16 + (g << 2) + i;
        O[(size_t)t * MD + cch] = acc[mf][nf][i] + bb;
      }
  }
}

// ------- flash attention: swapped 32x32, fixed-shift softmax, k-split ----
// (R14, verified 46.5us; explicit smem layout)
__global__ __launch_bounds__(512) void attn_fwd(const unsigned short* __restrict__ Qg,
                                                const unsigned short* __restrict__ Kg,
                                                const unsigned short* __restrict__ Vg,
                                                unsigned short* __restrict__ Xout) {
  // [0,32768) K = [half][2 buf][8192B]; [32768,65536) V = [half][2 buf][8192B]
  __shared__ __align__(16) char smem[65536];
  char* sKc = smem;
  char* sVc = smem + 32768;

  const int tid  = threadIdx.x;
  const int lane = tid & 63;
  const int wave = tid >> 6;           // 0..7
  const int ws   = wave & 3;           // q-subtile
  const int grp  = wave >> 2;          // k-half
  const int l31  = lane & 31;
  const int half = lane >> 5;
  const int bh   = blockIdx.y;
  const int q0w  = (blockIdx.x << 7) + (ws << 5);

  const unsigned short* Qb = Qg + (size_t)bh * (SEQ * HD);
  const char* Kb = (const char*)(Kg + (size_t)bh * (SEQ * HD));
  const char* Vb = (const char*)(Vg + (size_t)bh * (HD * SEQ));

  bf16x8 qf[4];
#pragma unroll
  for (int c = 0; c < 4; ++c)
    qf[c] = *(const bf16x8*)&Qb[(size_t)(q0w + l31) * HD + c * 16 + half * 8];

  f32x16 acc_o[2];
#pragma unroll
  for (int dt = 0; dt < 2; ++dt)
#pragma unroll
    for (int e = 0; e < 16; ++e) acc_o[dt][e] = 0.f;
  float lrow = 0.f;

  auto stage = [&](int c, int kt) {
#pragma unroll
    for (int h = 0; h < 2; ++h) {
      const int p = tid << 4;
      const int row = p >> 7;
      const int lcol = (p ^ ((row & 7) << 4)) & 127;
      const int kbase = (h << 10) + (kt << 6);
      gload_lds16(Kb + (size_t)(kbase + row) * (HD * 2) + lcol,
                  sKc + ((h * 2 + c) << 13) + p);
      gload_lds16(Vb + (size_t)row * (SEQ * 2) + (kbase << 1) + lcol,
                  sVc + ((h * 2 + c) << 13) + p);
    }
  };

  const char* myK = sKc + (grp << 14);
  const char* myV = sVc + (grp << 14);

  stage(0, 0);
  __syncthreads();
  int cur = 0;

  const int NT = SEQ / 2 / 64;   // 16 tiles per half
  for (int kt = 0; kt < NT; ++kt) {
    if (kt + 1 < NT) stage(cur ^ 1, kt + 1);

    f32x16 accs[2];
    __builtin_amdgcn_s_setprio(1);
#pragma unroll
    for (int ks = 0; ks < 2; ++ks) {
#pragma unroll
      for (int e = 0; e < 16; ++e) accs[ks][e] = 0.f;
      const int krow = ks * 32 + l31;
      const int swz  = (krow & 7) << 4;
#pragma unroll
      for (int c = 0; c < 4; ++c) {
        const int off = (krow << 7) + ((c * 32 + half * 16) ^ swz);
        bf16x8 kf = *(const bf16x8*)(myK + ((cur) << 13) + off);
        accs[ks] = __builtin_amdgcn_mfma_f32_32x32x16_bf16(kf, qf[c], accs[ks], 0, 0, 0);
      }
    }
    __builtin_amdgcn_s_setprio(0);

    float rsum = 0.f;
#pragma unroll
    for (int ks = 0; ks < 2; ++ks)
#pragma unroll
      for (int e = 0; e < 16; ++e) {
        const float pv = __builtin_amdgcn_exp2f(accs[ks][e]);
        accs[ks][e] = pv;
        rsum += pv;
      }
    lrow += rsum;

    bf16x8 pa[4];
#pragma unroll
    for (int ks = 0; ks < 2; ++ks)
#pragma unroll
      for (int hc = 0; hc < 2; ++hc) {
        const int b = hc * 8;
        unsigned X  = cvtpk(accs[ks][b + 0], accs[ks][b + 1]);
        unsigned X2 = cvtpk(accs[ks][b + 2], accs[ks][b + 3]);
        unsigned Y  = cvtpk(accs[ks][b + 4], accs[ks][b + 5]);
        unsigned Y2 = cvtpk(accs[ks][b + 6], accs[ks][b + 7]);
        plswap(X, Y);
        plswap(X2, Y2);
        union { unsigned u[4]; bf16x8 v; } w;
        w.u[0] = X; w.u[1] = X2; w.u[2] = Y; w.u[3] = Y2;
        pa[ks * 2 + hc] = w.v;
      }

    __builtin_amdgcn_s_setprio(1);
#pragma unroll
    for (int dt = 0; dt < 2; ++dt) {
      const int drow = dt * 32 + l31;
      const int swz  = (drow & 7) << 4;
#pragma unroll
      for (int kc = 0; kc < 4; ++kc) {
        const int off = (drow << 7) + ((kc * 32 + half * 16) ^ swz);
        bf16x8 vf = *(const bf16x8*)(myV + ((cur) << 13) + off);
        acc_o[dt] = __builtin_amdgcn_mfma_f32_32x32x16_bf16(vf, pa[kc], acc_o[dt], 0, 0, 0);
      }
    }
    __builtin_amdgcn_s_setprio(0);

    __syncthreads();
    cur ^= 1;
  }

  // ---- k-half combine via LDS (aliases smem front; 35328B < 65536B) ----
  float lt = lrow + __shfl_xor(lrow, 32);   // this half's full row sum
  float* dump  = (float*)smem;              // [ws][32 q][68 d] fp32 (pad 68)
  float* ldump = dump + 4 * 32 * 68;
  const int base = (ws * 32 + l31) * 68;

  if (grp == 1) {
#pragma unroll
    for (int dt = 0; dt < 2; ++dt)
#pragma unroll
      for (int r4 = 0; r4 < 4; ++r4) {
        const int d0 = dt * 32 + r4 * 8 + half * 4;
        const int e = r4 * 4;
        *(float2*)&dump[base + d0]     = float2{acc_o[dt][e + 0], acc_o[dt][e + 1]};
        *(float2*)&dump[base + d0 + 2] = float2{acc_o[dt][e + 2], acc_o[dt][e + 3]};
      }
    if (half == 0) ldump[ws * 32 + l31] = lt;
  }
  __syncthreads();
  if (grp == 0) {
    const float ltot = lt + ldump[ws * 32 + l31];
    const float inv = 1.f / ltot;
    const int b = bh >> 4, h = bh & 15;
    const int s = q0w + l31;
    const int t = s * NBATCH + b;
    unsigned short* Ot = Xout + (size_t)t * MD + (h << 6);
#pragma unroll
    for (int dt = 0; dt < 2; ++dt)
#pragma unroll
      for (int r4 = 0; r4 < 4; ++r4) {
        const int d0 = dt * 32 + r4 * 8 + half * 4;
        const int e = r4 * 4;
        float2 a0 = *(float2*)&dump[base + d0];
        float2 a1 = *(float2*)&dump[base + d0 + 2];
        uint2 w;
        w.x = cvtpk((acc_o[dt][e + 0] + a0.x) * inv, (acc_o[dt][e + 1] + a0.y) * inv);
        w.y = cvtpk((acc_o[dt][e + 2] + a1.x) * inv, (acc_o[dt][e + 3] + a1.y) * inv);
        *(uint2*)(Ot + d0) = w;
      }
  }
}

extern "C" void kernel_launch(void* const* d_in, const int* in_sizes, int n_in,
                              void* d_out, int out_size, void* d_ws, size_t ws_size,
                              hipStream_t stream) {
  const float* query = (const float*)d_in[0];
  const float* key   = (const float*)d_in[1];
  const float* value = (const float*)d_in[2];
  // d_in[3] = mask: dead code in reference
  const float* Wq = (const float*)d_in[4];
  const float* bq = (const float*)d_in[5];
  const float* Wk = (const float*)d_in[6];
  const float* bk = (const float*)d_in[7];
  const float* Wv = (const float*)d_in[8];
  const float* bv = (const float*)d_in[9];
  const float* Wo = (const float*)d_in[10];
  const float* bo = (const float*)d_in[11];

  char* ws = (char*)d_ws;
  const size_t MB = 1024 * 1024;
  unsigned short* Xa  = (unsigned short*)(ws + 0 * MB);   // attn out [TOK,MD] bf16
  unsigned short* Wqb = (unsigned short*)(ws + 24 * MB);
  unsigned short* Wkb = (unsigned short*)(ws + 26 * MB);
  unsigned short* Wvb = (unsigned short*)(ws + 28 * MB);
  unsigned short* Wob = (unsigned short*)(ws + 30 * MB);
  unsigned short* Qb  = (unsigned short*)(ws + 32 * MB);  // [B,H,S,D]
  unsigned short* Kb  = (unsigned short*)(ws + 40 * MB);  // [B,H,S,D]
  unsigned short* Vb  = (unsigned short*)(ws + 48 * MB);  // [B,H,D,S]

  cvt_w<<<4 * WN8 / 256, 256, 0, stream>>>(Wq, Wk, Wv, Wo, Wqb, Wkb, Wvb, Wob);

  const float kQScale = 0.125f * 1.44269504088896340736f;  // (1/sqrt(64))*log2(e)
  dim3 gQKV(MD / 128, TOK / 128, 3);   // (8, 32, 3) = 768 blocks, 16 waves
  gemm_qkv<<<gQKV, 1024, 0, stream>>>(query, key, value, Wqb, Wkb, Wvb,
                                      bq, bk, bv, Qb, Kb, Vb, kQScale);

  dim3 gA(SEQ / 128, NBATCH * NHEAD);  // (16, 32) = 512 blocks, 8 waves each
  attn_fwd<<<gA, 512, 0, stream>>>(Qb, Kb, Vb, Xa);

  dim3 gO(MD / 128, TOK / 128);        // (8, 32) = 256 blocks, 16 waves each
  gemm_oproj<<<gO, 1024, 0, stream>>>(Xa, Wob, bo, (float*)d_out);
  (void)in_sizes; (void)n_in; (void)out_size; (void)ws_size;
}

// Round 16
// 110.373 us; speedup vs baseline: 1.0140x; 1.0140x over previous
//
#include <hip/hip_runtime.h>

#define SEQ    2048
#define NBATCH 2
#define NHEAD  16
#define HD     64
#define MD     1024
#define TOK    (SEQ * NBATCH)   // 4096
#define XN8    (TOK * MD / 8)   // 524288 = 2^19
#define WN8    (MD * MD / 8)    // 131072 = 2^17

typedef __attribute__((ext_vector_type(4)))  float f32x4;
typedef __attribute__((ext_vector_type(16))) float f32x16;
typedef __attribute__((ext_vector_type(8)))  short bf16x8;
typedef __attribute__((ext_vector_type(8)))  unsigned short u16x8;

__device__ __forceinline__ unsigned short f2bf(float f) {
  union { float f; unsigned int u; } x; x.f = f;
  unsigned int u = x.u + 0x7fffu + ((x.u >> 16) & 1u);   // RNE; inputs are finite
  return (unsigned short)(u >> 16);
}

// v_cvt_pk_bf16_f32: D[15:0]=bf16(lo), D[31:16]=bf16(hi)  (no builtin on gfx950)
__device__ __forceinline__ unsigned cvtpk(float lo, float hi) {
  unsigned r;
  asm("v_cvt_pk_bf16_f32 %0, %1, %2" : "=v"(r) : "v"(lo), "v"(hi));
  return r;
}
// v_permlane32_swap_b32: a' = (a_lo | b_lo), b' = (a_hi | b_hi)
__device__ __forceinline__ void plswap(unsigned &a, unsigned &b) {
  asm volatile("v_permlane32_swap_b32 %0, %1" : "+v"(a), "+v"(b));
}

__device__ __forceinline__ void gload_lds16(const void* g, void* l) {
  typedef const __attribute__((address_space(1))) unsigned int* gp_t;
  typedef __attribute__((address_space(3))) unsigned int* lp_t;
  __builtin_amdgcn_global_load_lds((gp_t)g, (lp_t)l, 16, 0, 0);
}

// -------- fp32 -> bf16 convert, all 7 tensors in one launch --------------
__global__ __launch_bounds__(256) void cvt_all(
    const float* __restrict__ q, const float* __restrict__ k, const float* __restrict__ v,
    const float* __restrict__ wq, const float* __restrict__ wk,
    const float* __restrict__ wv, const float* __restrict__ wo,
    unsigned short* __restrict__ oq, unsigned short* __restrict__ ok,
    unsigned short* __restrict__ ov, unsigned short* __restrict__ owq,
    unsigned short* __restrict__ owk, unsigned short* __restrict__ owv,
    unsigned short* __restrict__ owo) {
  const int i = blockIdx.x * 256 + threadIdx.x;
  const float* src; unsigned short* dst; int r;
  if (i < 3 * XN8) {                 // boundaries 256-aligned: no divergence
    const int s = i >> 19; r = i & (XN8 - 1);
    src = s == 0 ? q : (s == 1 ? k : v);
    dst = s == 0 ? oq : (s == 1 ? ok : ov);
  } else {
    const int j = i - 3 * XN8; const int s = j >> 17; r = j & (WN8 - 1);
    src = s == 0 ? wq : (s == 1 ? wk : (s == 2 ? wv : wo));
    dst = s == 0 ? owq : (s == 1 ? owk : (s == 2 ? owv : owo));
  }
  const float4* p = (const float4*)src + (size_t)r * 2;
  float4 a = p[0];
  float4 b = p[1];
  u16x8 o;
  o[0] = f2bf(a.x); o[1] = f2bf(a.y); o[2] = f2bf(a.z); o[3] = f2bf(a.w);
  o[4] = f2bf(b.x); o[5] = f2bf(b.y); o[6] = f2bf(b.z); o[7] = f2bf(b.w);
  *((u16x8*)dst + r) = o;
}

// ---- fused QKV projection, R16: UNIFORM 16-wave bf16 GEMM — exact clone
// of the verified R14 oproj structure (1 gload_lds/thread/tile, steady
// vmcnt(1), 3 buffers) + T1 768-block XCD swizzle + z-dispatch epilogues.
// Grid 768 = 2 resident blocks/CU x 16 waves = 100% occupancy.
__global__ __launch_bounds__(1024) void gemm_qkv(
    const unsigned short* __restrict__ Xq, const unsigned short* __restrict__ Xk,
    const unsigned short* __restrict__ Xv, const unsigned short* __restrict__ Wq,
    const unsigned short* __restrict__ Wk, const unsigned short* __restrict__ Wv,
    const float* __restrict__ bq, const float* __restrict__ bk, const float* __restrict__ bv,
    unsigned short* __restrict__ Qo, unsigned short* __restrict__ Ko,
    unsigned short* __restrict__ Vo, float qscale) {
  __shared__ unsigned short sA[3][128 * 32];
  __shared__ unsigned short sB[3][128 * 32];
  const int tid  = threadIdx.x;
  const int lane = tid & 63;
  const int wave = tid >> 6;            // 0..15
  const int wm   = (wave >> 2) << 5;    // 4 M-waves x 32
  const int wn   = (wave & 3) << 5;     // 4 N-waves x 32
  const int l15  = lane & 15;
  const int g    = lane >> 4;

  // T1 swizzle decode: flat = x + 8y + 256z; f(x,gr)=64*(gr>>3)+8x+(gr&7),
  // gr = y + 32z. All 8 x-blocks of a group share flat%8 -> one XCD.
  const int flat = blockIdx.x + (blockIdx.y << 3) + (blockIdx.z << 8);
  const int nx   = (flat & 63) >> 3;               // N-tile 0..7
  const int gr   = ((flat >> 6) << 3) + (flat & 7);// group 0..95
  const int ny   = gr & 31;                        // M-tile 0..31
  const int z    = gr >> 5;                        // 0..2

  const unsigned short* A; const unsigned short* B; const float* bias;
  if (z == 0)      { A = Xq; B = Wq; bias = bq; }
  else if (z == 1) { A = Xk; B = Wk; bias = bk; }
  else             { A = Wv; B = Xv; bias = bv; }
  int bM, bN;
  if (z < 2) { bM = ny << 7; bN = nx << 7; }       // shared panel = A (X)
  else       { bM = nx << 7; bN = ny << 7; }       // shared panel = B (Xv)

  f32x4 acc[2][2];
#pragma unroll
  for (int a_ = 0; a_ < 2; ++a_)
#pragma unroll
    for (int b_ = 0; b_ < 2; ++b_)
      acc[a_][b_] = f32x4{0.f, 0.f, 0.f, 0.f};

  // staging: ct indexes the 512 16B-chunks of one 8KB tile;
  // tid<512 -> A side, tid>=512 -> B side. 1 load/thread/tile.
  const int ct = tid & 511;
  const int r = ct >> 2, cc = ct & 3;
  const unsigned short* srow = (tid < 512)
      ? A + (size_t)(bM + r) * MD + cc * 8
      : B + (size_t)(bN + r) * MD + cc * 8;
  unsigned short* sdst3 = (tid < 512) ? &sA[0][0] : &sB[0][0];
  auto stage = [&](int c, int kt) {
    gload_lds16(srow + (kt << 5), (char*)(sdst3 + c * 4096) + ct * 16);
  };

  const int nk = MD >> 5;               // 32
  stage(0, 0);
  stage(1, 1);
  asm volatile("s_waitcnt vmcnt(1)" ::: "memory");   // tile 0 landed
  __builtin_amdgcn_s_barrier();

  int cur = 0;
  for (int kt = 0; kt < nk; ++kt) {
    if (kt + 2 < nk) stage(cur == 0 ? 2 : cur - 1, kt + 2);
    bf16x8 af[2], bfr[2];
#pragma unroll
    for (int f = 0; f < 2; ++f)
      af[f] = *(const bf16x8*)&sA[cur][(wm + f * 16 + l15) * 32 + g * 8];
#pragma unroll
    for (int f = 0; f < 2; ++f)
      bfr[f] = *(const bf16x8*)&sB[cur][(wn + f * 16 + l15) * 32 + g * 8];
#pragma unroll
    for (int mf = 0; mf < 2; ++mf)
#pragma unroll
      for (int nf = 0; nf < 2; ++nf)
        acc[mf][nf] = __builtin_amdgcn_mfma_f32_16x16x32_bf16(af[mf], bfr[nf], acc[mf][nf], 0, 0, 0);
    if (kt + 2 < nk)
      asm volatile("s_waitcnt vmcnt(1)" ::: "memory");   // tile kt+1 landed
    else if (kt + 1 < nk)
      asm volatile("s_waitcnt vmcnt(0)" ::: "memory");
    if (kt + 1 < nk) __builtin_amdgcn_s_barrier();
    cur = (cur == 2) ? 0 : cur + 1;
  }

  if (z < 2) {
    unsigned short* O = (z == 0) ? Qo : Ko;
    const float scale = (z == 0) ? qscale : 1.0f;
#pragma unroll
    for (int nf = 0; nf < 2; ++nf) {
      const int cch = bN + wn + nf * 16 + l15;
      const float bb = bias[cch];
      const int h = cch >> 6, d = cch & 63;
#pragma unroll
      for (int mf = 0; mf < 2; ++mf)
#pragma unroll
        for (int i = 0; i < 4; ++i) {
          const int t = bM + wm + mf * 16 + (g << 2) + i;
          const int b = t & 1, s = t >> 1;
          O[((((b << 4) + h) * SEQ + s) << 6) + d] = f2bf((acc[mf][nf][i] + bb) * scale);
        }
    }
  } else {
#pragma unroll
    for (int mf = 0; mf < 2; ++mf)
#pragma unroll
      for (int i = 0; i < 4; ++i) {
        const int rch = bM + wm + mf * 16 + (g << 2) + i;
        const float bb = bias[rch];
        const int h = rch >> 6, d = rch & 63;
#pragma unroll
        for (int nf = 0; nf < 2; ++nf) {
          const int t = bN + wn + nf * 16 + l15;
          const int b = t & 1, s = t >> 1;
          Vo[((((b << 4) + h) << 6) + d) * SEQ + s] = f2bf(acc[mf][nf][i] + bb);
        }
      }
  }
}

// -------- O projection: fp32 out, 16 waves, counted-vmcnt + T1 swizzle ----
// (R14, verified)
__global__ __launch_bounds__(1024) void gemm_oproj(const unsigned short* __restrict__ A,
                                                   const unsigned short* __restrict__ B,
                                                   const float* __restrict__ bias,
                                                   float* __restrict__ O) {
  __shared__ unsigned short sA[3][128 * 32];
  __shared__ unsigned short sB[3][128 * 32];
  const int tid  = threadIdx.x;
  const int lane = tid & 63;
  const int wave = tid >> 6;            // 0..15
  const int wm   = (wave >> 2) << 5;    // 4 M-waves x 32
  const int wn   = (wave & 3) << 5;     // 4 N-waves x 32
  const int l15  = lane & 15;
  const int g    = lane >> 4;

  // T1 swizzle: 8 N-blocks sharing an A panel -> same XCD (gr = y, 0..31)
  const int flat = blockIdx.x + (blockIdx.y << 3);   // 0..255
  const int nx   = (flat & 63) >> 3;
  const int gr   = ((flat >> 6) << 3) + (flat & 7);  // 0..31
  const int bM   = gr << 7;
  const int bN   = nx << 7;

  f32x4 acc[2][2];
#pragma unroll
  for (int a_ = 0; a_ < 2; ++a_)
#pragma unroll
    for (int b_ = 0; b_ < 2; ++b_)
      acc[a_][b_] = f32x4{0.f, 0.f, 0.f, 0.f};

  const int ct = tid & 511;
  const int r = ct >> 2, cc = ct & 3;
  const unsigned short* srow = (tid < 512)
      ? A + (size_t)(bM + r) * MD + cc * 8
      : B + (size_t)(bN + r) * MD + cc * 8;
  unsigned short* sdst3 = (tid < 512) ? &sA[0][0] : &sB[0][0];
  auto stage = [&](int c, int kt) {
    gload_lds16(srow + (kt << 5), (char*)(sdst3 + c * 4096) + ct * 16);
  };

  const int nk = MD >> 5;
  stage(0, 0);
  stage(1, 1);
  asm volatile("s_waitcnt vmcnt(1)" ::: "memory");   // tile 0 landed
  __builtin_amdgcn_s_barrier();

  int cur = 0;
  for (int kt = 0; kt < nk; ++kt) {
    if (kt + 2 < nk) stage(cur == 0 ? 2 : cur - 1, kt + 2);
    bf16x8 af[2], bfr[2];
#pragma unroll
    for (int f = 0; f < 2; ++f)
      af[f] = *(const bf16x8*)&sA[cur][(wm + f * 16 + l15) * 32 + g * 8];
#pragma unroll
    for (int f = 0; f < 2; ++f)
      bfr[f] = *(const bf16x8*)&sB[cur][(wn + f * 16 + l15) * 32 + g * 8];
#pragma unroll
    for (int mf = 0; mf < 2; ++mf)
#pragma unroll
      for (int nf = 0; nf < 2; ++nf)
        acc[mf][nf] = __builtin_amdgcn_mfma_f32_16x16x32_bf16(af[mf], bfr[nf], acc[mf][nf], 0, 0, 0);
    if (kt + 2 < nk)
      asm volatile("s_waitcnt vmcnt(1)" ::: "memory");   // tile kt+1 landed
    else if (kt + 1 < nk)
      asm volatile("s_waitcnt vmcnt(0)" ::: "memory");
    if (kt + 1 < nk) __builtin_amdgcn_s_barrier();
    cur = (cur == 2) ? 0 : cur + 1;
  }

#pragma unroll
  for (int nf = 0; nf < 2; ++nf) {
    const int cch = bN + wn + nf * 16 + l15;
    const float bb = bias[cch];
#pragma unroll
    for (int mf = 0; mf < 2; ++mf)
#pragma unroll
      for (int i = 0; i < 4; ++i) {
        const int t = bM + wm + mf * 16 + (g << 2) + i;
        O[(size_t)t * MD + cch] = acc[mf][nf][i] + bb;
      }
  }
}

// ------- flash attention: swapped 32x32, fixed-shift softmax, k-split ----
// (R14, verified 46.5us; explicit smem layout)
__global__ __launch_bounds__(512) void attn_fwd(const unsigned short* __restrict__ Qg,
                                                const unsigned short* __restrict__ Kg,
                                                const unsigned short* __restrict__ Vg,
                                                unsigned short* __restrict__ Xout) {
  // [0,32768) K = [half][2 buf][8192B]; [32768,65536) V = [half][2 buf][8192B]
  __shared__ __align__(16) char smem[65536];
  char* sKc = smem;
  char* sVc = smem + 32768;

  const int tid  = threadIdx.x;
  const int lane = tid & 63;
  const int wave = tid >> 6;           // 0..7
  const int ws   = wave & 3;           // q-subtile
  const int grp  = wave >> 2;          // k-half
  const int l31  = lane & 31;
  const int half = lane >> 5;
  const int bh   = blockIdx.y;
  const int q0w  = (blockIdx.x << 7) + (ws << 5);

  const unsigned short* Qb = Qg + (size_t)bh * (SEQ * HD);
  const char* Kb = (const char*)(Kg + (size_t)bh * (SEQ * HD));
  const char* Vb = (const char*)(Vg + (size_t)bh * (HD * SEQ));

  bf16x8 qf[4];
#pragma unroll
  for (int c = 0; c < 4; ++c)
    qf[c] = *(const bf16x8*)&Qb[(size_t)(q0w + l31) * HD + c * 16 + half * 8];

  f32x16 acc_o[2];
#pragma unroll
  for (int dt = 0; dt < 2; ++dt)
#pragma unroll
    for (int e = 0; e < 16; ++e) acc_o[dt][e] = 0.f;
  float lrow = 0.f;

  auto stage = [&](int c, int kt) {
#pragma unroll
    for (int h = 0; h < 2; ++h) {
      const int p = tid << 4;
      const int row = p >> 7;
      const int lcol = (p ^ ((row & 7) << 4)) & 127;
      const int kbase = (h << 10) + (kt << 6);
      gload_lds16(Kb + (size_t)(kbase + row) * (HD * 2) + lcol,
                  sKc + ((h * 2 + c) << 13) + p);
      gload_lds16(Vb + (size_t)row * (SEQ * 2) + (kbase << 1) + lcol,
                  sVc + ((h * 2 + c) << 13) + p);
    }
  };

  const char* myK = sKc + (grp << 14);
  const char* myV = sVc + (grp << 14);

  stage(0, 0);
  __syncthreads();
  int cur = 0;

  const int NT = SEQ / 2 / 64;   // 16 tiles per half
  for (int kt = 0; kt < NT; ++kt) {
    if (kt + 1 < NT) stage(cur ^ 1, kt + 1);

    f32x16 accs[2];
    __builtin_amdgcn_s_setprio(1);
#pragma unroll
    for (int ks = 0; ks < 2; ++ks) {
#pragma unroll
      for (int e = 0; e < 16; ++e) accs[ks][e] = 0.f;
      const int krow = ks * 32 + l31;
      const int swz  = (krow & 7) << 4;
#pragma unroll
      for (int c = 0; c < 4; ++c) {
        const int off = (krow << 7) + ((c * 32 + half * 16) ^ swz);
        bf16x8 kf = *(const bf16x8*)(myK + ((cur) << 13) + off);
        accs[ks] = __builtin_amdgcn_mfma_f32_32x32x16_bf16(kf, qf[c], accs[ks], 0, 0, 0);
      }
    }
    __builtin_amdgcn_s_setprio(0);

    float rsum = 0.f;
#pragma unroll
    for (int ks = 0; ks < 2; ++ks)
#pragma unroll
      for (int e = 0; e < 16; ++e) {
        const float pv = __builtin_amdgcn_exp2f(accs[ks][e]);
        accs[ks][e] = pv;
        rsum += pv;
      }
    lrow += rsum;

    bf16x8 pa[4];
#pragma unroll
    for (int ks = 0; ks < 2; ++ks)
#pragma unroll
      for (int hc = 0; hc < 2; ++hc) {
        const int b = hc * 8;
        unsigned X  = cvtpk(accs[ks][b + 0], accs[ks][b + 1]);
        unsigned X2 = cvtpk(accs[ks][b + 2], accs[ks][b + 3]);
        unsigned Y  = cvtpk(accs[ks][b + 4], accs[ks][b + 5]);
        unsigned Y2 = cvtpk(accs[ks][b + 6], accs[ks][b + 7]);
        plswap(X, Y);
        plswap(X2, Y2);
        union { unsigned u[4]; bf16x8 v; } w;
        w.u[0] = X; w.u[1] = X2; w.u[2] = Y; w.u[3] = Y2;
        pa[ks * 2 + hc] = w.v;
      }

    __builtin_amdgcn_s_setprio(1);
#pragma unroll
    for (int dt = 0; dt < 2; ++dt) {
      const int drow = dt * 32 + l31;
      const int swz  = (drow & 7) << 4;
#pragma unroll
      for (int kc = 0; kc < 4; ++kc) {
        const int off = (drow << 7) + ((kc * 32 + half * 16) ^ swz);
        bf16x8 vf = *(const bf16x8*)(myV + ((cur) << 13) + off);
        acc_o[dt] = __builtin_amdgcn_mfma_f32_32x32x16_bf16(vf, pa[kc], acc_o[dt], 0, 0, 0);
      }
    }
    __builtin_amdgcn_s_setprio(0);

    __syncthreads();
    cur ^= 1;
  }

  // ---- k-half combine via LDS (aliases smem front; 35328B < 65536B) ----
  float lt = lrow + __shfl_xor(lrow, 32);   // this half's full row sum
  float* dump  = (float*)smem;              // [ws][32 q][68 d] fp32 (pad 68)
  float* ldump = dump + 4 * 32 * 68;
  const int base = (ws * 32 + l31) * 68;

  if (grp == 1) {
#pragma unroll
    for (int dt = 0; dt < 2; ++dt)
#pragma unroll
      for (int r4 = 0; r4 < 4; ++r4) {
        const int d0 = dt * 32 + r4 * 8 + half * 4;
        const int e = r4 * 4;
        *(float2*)&dump[base + d0]     = float2{acc_o[dt][e + 0], acc_o[dt][e + 1]};
        *(float2*)&dump[base + d0 + 2] = float2{acc_o[dt][e + 2], acc_o[dt][e + 3]};
      }
    if (half == 0) ldump[ws * 32 + l31] = lt;
  }
  __syncthreads();
  if (grp == 0) {
    const float ltot = lt + ldump[ws * 32 + l31];
    const float inv = 1.f / ltot;
    const int b = bh >> 4, h = bh & 15;
    const int s = q0w + l31;
    const int t = s * NBATCH + b;
    unsigned short* Ot = Xout + (size_t)t * MD + (h << 6);
#pragma unroll
    for (int dt = 0; dt < 2; ++dt)
#pragma unroll
      for (int r4 = 0; r4 < 4; ++r4) {
        const int d0 = dt * 32 + r4 * 8 + half * 4;
        const int e = r4 * 4;
        float2 a0 = *(float2*)&dump[base + d0];
        float2 a1 = *(float2*)&dump[base + d0 + 2];
        uint2 w;
        w.x = cvtpk((acc_o[dt][e + 0] + a0.x) * inv, (acc_o[dt][e + 1] + a0.y) * inv);
        w.y = cvtpk((acc_o[dt][e + 2] + a1.x) * inv, (acc_o[dt][e + 3] + a1.y) * inv);
        *(uint2*)(Ot + d0) = w;
      }
  }
}

extern "C" void kernel_launch(void* const* d_in, const int* in_sizes, int n_in,
                              void* d_out, int out_size, void* d_ws, size_t ws_size,
                              hipStream_t stream) {
  const float* query = (const float*)d_in[0];
  const float* key   = (const float*)d_in[1];
  const float* value = (const float*)d_in[2];
  // d_in[3] = mask: dead code in reference
  const float* Wq = (const float*)d_in[4];
  const float* bq = (const float*)d_in[5];
  const float* Wk = (const float*)d_in[6];
  const float* bk = (const float*)d_in[7];
  const float* Wv = (const float*)d_in[8];
  const float* bv = (const float*)d_in[9];
  const float* Wo = (const float*)d_in[10];
  const float* bo = (const float*)d_in[11];

  char* ws = (char*)d_ws;
  const size_t MB = 1024 * 1024;
  unsigned short* Xq  = (unsigned short*)(ws + 0 * MB);   // [TOK,MD] bf16
  unsigned short* Xk  = (unsigned short*)(ws + 8 * MB);
  unsigned short* Xv  = (unsigned short*)(ws + 16 * MB);
  unsigned short* Wqb = (unsigned short*)(ws + 24 * MB);
  unsigned short* Wkb = (unsigned short*)(ws + 26 * MB);
  unsigned short* Wvb = (unsigned short*)(ws + 28 * MB);
  unsigned short* Wob = (unsigned short*)(ws + 30 * MB);
  unsigned short* Qb  = (unsigned short*)(ws + 32 * MB);  // [B,H,S,D]
  unsigned short* Kb  = (unsigned short*)(ws + 40 * MB);  // [B,H,S,D]
  unsigned short* Vb  = (unsigned short*)(ws + 48 * MB);  // [B,H,D,S]
  unsigned short* Xa  = Xq;  // alias: Xq dead after Q projection

  cvt_all<<<(3 * XN8 + 4 * WN8) / 256, 256, 0, stream>>>(
      query, key, value, Wq, Wk, Wv, Wo, Xq, Xk, Xv, Wqb, Wkb, Wvb, Wob);

  const float kQScale = 0.125f * 1.44269504088896340736f;  // (1/sqrt(64))*log2(e)
  dim3 gQKV(MD / 128, TOK / 128, 3);   // (8, 32, 3) = 768 blocks, 16 waves
  gemm_qkv<<<gQKV, 1024, 0, stream>>>(Xq, Xk, Xv, Wqb, Wkb, Wvb,
                                      bq, bk, bv, Qb, Kb, Vb, kQScale);

  dim3 gA(SEQ / 128, NBATCH * NHEAD);  // (16, 32) = 512 blocks, 8 waves each
  attn_fwd<<<gA, 512, 0, stream>>>(Qb, Kb, Vb, Xa);

  dim3 gO(MD / 128, TOK / 128);        // (8, 32) = 256 blocks, 16 waves each
  gemm_oproj<<<gO, 1024, 0, stream>>>(Xa, Wob, bo, (float*)d_out);
  (void)in_sizes; (void)n_in; (void)out_size; (void)ws_size;
}

// Round 17
// 107.926 us; speedup vs baseline: 1.0370x; 1.0227x over previous
//
#include <hip/hip_runtime.h>

#define SEQ    2048
#define NBATCH 2
#define NHEAD  16
#define HD     64
#define MD     1024
#define TOK    (SEQ * NBATCH)   // 4096
#define WN8    (MD * MD / 8)    // 131072 = 2^17

typedef __attribute__((ext_vector_type(4)))  float f32x4;
typedef __attribute__((ext_vector_type(16))) float f32x16;
typedef __attribute__((ext_vector_type(8)))  short bf16x8;
typedef __attribute__((ext_vector_type(8)))  unsigned short u16x8;

__device__ __forceinline__ unsigned short f2bf(float f) {
  union { float f; unsigned int u; } x; x.f = f;
  unsigned int u = x.u + 0x7fffu + ((x.u >> 16) & 1u);   // RNE; inputs are finite
  return (unsigned short)(u >> 16);
}

// v_cvt_pk_bf16_f32: D[15:0]=bf16(lo), D[31:16]=bf16(hi)  (no builtin on gfx950)
__device__ __forceinline__ unsigned cvtpk(float lo, float hi) {
  unsigned r;
  asm("v_cvt_pk_bf16_f32 %0, %1, %2" : "=v"(r) : "v"(lo), "v"(hi));
  return r;
}
// v_permlane32_swap_b32: a' = (a_lo | b_lo), b' = (a_hi | b_hi)
__device__ __forceinline__ void plswap(unsigned &a, unsigned &b) {
  asm volatile("v_permlane32_swap_b32 %0, %1" : "+v"(a), "+v"(b));
}

__device__ __forceinline__ void gload_lds16(const void* g, void* l) {
  typedef const __attribute__((address_space(1))) unsigned int* gp_t;
  typedef __attribute__((address_space(3))) unsigned int* lp_t;
  __builtin_amdgcn_global_load_lds((gp_t)g, (lp_t)l, 16, 0, 0);
}

// -------- fp32 -> bf16 convert, weights only (X is fused into gemm_qkv) ---
__global__ __launch_bounds__(256) void cvt_w(
    const float* __restrict__ wq, const float* __restrict__ wk,
    const float* __restrict__ wv, const float* __restrict__ wo,
    unsigned short* __restrict__ owq, unsigned short* __restrict__ owk,
    unsigned short* __restrict__ owv, unsigned short* __restrict__ owo) {
  const int i = blockIdx.x * 256 + threadIdx.x;
  const int s = i >> 17;           // WN8 = 2^17; boundaries 256-aligned
  const int r = i & (WN8 - 1);
  const float* src = s == 0 ? wq : (s == 1 ? wk : (s == 2 ? wv : wo));
  unsigned short* dst = s == 0 ? owq : (s == 1 ? owk : (s == 2 ? owv : owo));
  const float4* p = (const float4*)src + (size_t)r * 2;
  float4 a = p[0];
  float4 b = p[1];
  u16x8 o;
  o[0] = f2bf(a.x); o[1] = f2bf(a.y); o[2] = f2bf(a.z); o[3] = f2bf(a.w);
  o[4] = f2bf(b.x); o[5] = f2bf(b.y); o[6] = f2bf(b.z); o[7] = f2bf(b.w);
  *((u16x8*)dst + r) = o;
}

// ---- fused cvt+QKV projection (R10/R14, verified): depth-2 X pipeline,
// T1 bijective XCD swizzle, 3-buffer LDS, counted vmcnt.
__global__ __launch_bounds__(512) void gemm_qkv(
    const float* __restrict__ Xq, const float* __restrict__ Xk,
    const float* __restrict__ Xv, const unsigned short* __restrict__ Wq,
    const unsigned short* __restrict__ Wk, const unsigned short* __restrict__ Wv,
    const float* __restrict__ bq, const float* __restrict__ bk, const float* __restrict__ bv,
    unsigned short* __restrict__ Qo, unsigned short* __restrict__ Ko,
    unsigned short* __restrict__ Vo, float qscale) {
  __shared__ unsigned short sA[3][128 * 32];   // M-side
  __shared__ unsigned short sB[3][128 * 32];   // N-side
  const int tid  = threadIdx.x;
  const int lane = tid & 63;
  const int wave = tid >> 6;            // 0..7
  const int wm   = (wave >> 2) << 6;    // 2 M-waves x 64
  const int wn   = (wave & 3) << 5;     // 4 N-waves x 32
  const int l15  = lane & 15;
  const int g    = lane >> 4;

  // T1 swizzle decode: flat = x + 8y + 256z; f(x,gr)=64*(gr>>3)+8x+(gr&7),
  // gr = y + 32z. All 8 x-blocks of a group share flat%8 -> one XCD.
  const int flat = blockIdx.x + (blockIdx.y << 3) + (blockIdx.z << 8);
  const int nx   = (flat & 63) >> 3;               // N-tile 0..7
  const int gr   = ((flat >> 6) << 3) + (flat & 7);// group 0..95
  const int ny   = gr & 31;                        // M-tile 0..31
  const int z    = gr >> 5;                        // 0..2

  const float* Xf; const unsigned short* Wb; const float* bias;
  if (z == 0)      { Xf = Xq; Wb = Wq; bias = bq; }
  else if (z == 1) { Xf = Xk; Wb = Wk; bias = bk; }
  else             { Xf = Xv; Wb = Wv; bias = bv; }
  int bM, bN;
  if (z < 2) { bM = ny << 7; bN = nx << 7; }
  else       { bM = nx << 7; bN = ny << 7; }
  const int bX = (z < 2) ? bM : bN;     // X (token) side base row
  const int bW = (z < 2) ? bN : bM;     // W (channel) side base row
  unsigned short* sX3 = (z < 2) ? &sA[0][0] : &sB[0][0];
  unsigned short* sW3 = (z < 2) ? &sB[0][0] : &sA[0][0];

  f32x4 acc[4][2];
#pragma unroll
  for (int a_ = 0; a_ < 4; ++a_)
#pragma unroll
    for (int b_ = 0; b_ < 2; ++b_)
      acc[a_][b_] = f32x4{0.f, 0.f, 0.f, 0.f};

  const int r = tid >> 2, cc = tid & 3;
  const float* xsrc = Xf + (size_t)(bX + r) * MD + cc * 8;
  const unsigned short* wsrc = Wb + (size_t)(bW + r) * MD + cc * 8;

  // two named X reg sets (static indexing; rule #20)
  float4 ra0, rb0, ra1, rb1;
  auto xissue0 = [&](int kt) {
    ra0 = *(const float4*)(xsrc + (kt << 5));
    rb0 = *(const float4*)(xsrc + (kt << 5) + 4);
  };
  auto xissue1 = [&](int kt) {
    ra1 = *(const float4*)(xsrc + (kt << 5));
    rb1 = *(const float4*)(xsrc + (kt << 5) + 4);
  };
  auto xwrite0 = [&](int c) {
    union { unsigned u[4]; bf16x8 v; } w;
    w.u[0] = cvtpk(ra0.x, ra0.y); w.u[1] = cvtpk(ra0.z, ra0.w);
    w.u[2] = cvtpk(rb0.x, rb0.y); w.u[3] = cvtpk(rb0.z, rb0.w);
    *(bf16x8*)(sX3 + c * 4096 + tid * 8) = w.v;
  };
  auto xwrite1 = [&](int c) {
    union { unsigned u[4]; bf16x8 v; } w;
    w.u[0] = cvtpk(ra1.x, ra1.y); w.u[1] = cvtpk(ra1.z, ra1.w);
    w.u[2] = cvtpk(rb1.x, rb1.y); w.u[3] = cvtpk(rb1.z, rb1.w);
    *(bf16x8*)(sX3 + c * 4096 + tid * 8) = w.v;
  };
  auto wissue = [&](int c, int kt) {
    gload_lds16(wsrc + (kt << 5), (char*)(sW3 + c * 4096) + tid * 16);
  };

  auto mfma_step = [&](int c) {
    bf16x8 af[4], bfr[2];
#pragma unroll
    for (int f = 0; f < 4; ++f)
      af[f] = *(const bf16x8*)&sA[c][(wm + f * 16 + l15) * 32 + g * 8];
#pragma unroll
    for (int f = 0; f < 2; ++f)
      bfr[f] = *(const bf16x8*)&sB[c][(wn + f * 16 + l15) * 32 + g * 8];
#pragma unroll
    for (int mf = 0; mf < 4; ++mf)
#pragma unroll
      for (int nf = 0; nf < 2; ++nf)
        acc[mf][nf] = __builtin_amdgcn_mfma_f32_16x16x32_bf16(af[mf], bfr[nf], acc[mf][nf], 0, 0, 0);
  };

  const int nk = MD >> 5;               // 32 (even)
  auto endwait = [&](int e) {
    if (e + 4 < nk)      asm volatile("s_waitcnt vmcnt(3)" ::: "memory");
    else if (e + 2 < nk) asm volatile("s_waitcnt vmcnt(1)" ::: "memory");
    else                 asm volatile("s_waitcnt vmcnt(0)" ::: "memory");
    asm volatile("s_waitcnt lgkmcnt(0)" ::: "memory");
    __builtin_amdgcn_s_barrier();
  };

  xissue0(0);
  xissue1(1);
  wissue(0, 0);
  wissue(1, 1);
  asm volatile("s_waitcnt vmcnt(4)" ::: "memory");   // X(0) landed
  xwrite0(0);
  asm volatile("s_waitcnt vmcnt(2)" ::: "memory");   // X(1) landed
  xwrite1(1);
  xissue0(2);
  xissue1(3);
  asm volatile("s_waitcnt vmcnt(4)" ::: "memory");   // W(0),W(1) landed
  asm volatile("s_waitcnt lgkmcnt(0)" ::: "memory");
  __builtin_amdgcn_s_barrier();

  for (int kt = 0; kt < nk; kt += 2) {
    if (kt + 2 < nk) { xwrite0((kt + 2) % 3); wissue((kt + 2) % 3, kt + 2); }
    if (kt + 4 < nk) xissue0(kt + 4);
    mfma_step(kt % 3);
    endwait(kt);
    if (kt + 3 < nk) { xwrite1((kt + 3) % 3); wissue((kt + 3) % 3, kt + 3); }
    if (kt + 5 < nk) xissue1(kt + 5);
    mfma_step((kt + 1) % 3);
    if (kt + 2 < nk) endwait(kt + 1);
  }

  if (z < 2) {
    unsigned short* O = (z == 0) ? Qo : Ko;
    const float scale = (z == 0) ? qscale : 1.0f;
#pragma unroll
    for (int nf = 0; nf < 2; ++nf) {
      const int cch = bN + wn + nf * 16 + l15;
      const float bb = bias[cch];
      const int h = cch >> 6, d = cch & 63;
#pragma unroll
      for (int mf = 0; mf < 4; ++mf)
#pragma unroll
        for (int i = 0; i < 4; ++i) {
          const int t = bM + wm + mf * 16 + (g << 2) + i;
          const int b = t & 1, s = t >> 1;
          O[((((b << 4) + h) * SEQ + s) << 6) + d] = f2bf((acc[mf][nf][i] + bb) * scale);
        }
    }
  } else {
#pragma unroll
    for (int mf = 0; mf < 4; ++mf)
#pragma unroll
      for (int i = 0; i < 4; ++i) {
        const int rch = bM + wm + mf * 16 + (g << 2) + i;
        const float bb = bias[rch];
        const int h = rch >> 6, d = rch & 63;
#pragma unroll
        for (int nf = 0; nf < 2; ++nf) {
          const int t = bN + wn + nf * 16 + l15;
          const int b = t & 1, s = t >> 1;
          Vo[((((b << 4) + h) << 6) + d) * SEQ + s] = f2bf(acc[mf][nf][i] + bb);
        }
      }
  }
}

// -------- O projection: fp32 out, 16 waves, counted-vmcnt + T1 swizzle ----
// (R14, verified)
__global__ __launch_bounds__(1024) void gemm_oproj(const unsigned short* __restrict__ A,
                                                   const unsigned short* __restrict__ B,
                                                   const float* __restrict__ bias,
                                                   float* __restrict__ O) {
  __shared__ unsigned short sA[3][128 * 32];
  __shared__ unsigned short sB[3][128 * 32];
  const int tid  = threadIdx.x;
  const int lane = tid & 63;
  const int wave = tid >> 6;            // 0..15
  const int wm   = (wave >> 2) << 5;    // 4 M-waves x 32
  const int wn   = (wave & 3) << 5;     // 4 N-waves x 32
  const int l15  = lane & 15;
  const int g    = lane >> 4;

  // T1 swizzle: 8 N-blocks sharing an A panel -> same XCD (gr = y, 0..31)
  const int flat = blockIdx.x + (blockIdx.y << 3);   // 0..255
  const int nx   = (flat & 63) >> 3;
  const int gr   = ((flat >> 6) << 3) + (flat & 7);  // 0..31
  const int bM   = gr << 7;
  const int bN   = nx << 7;

  f32x4 acc[2][2];
#pragma unroll
  for (int a_ = 0; a_ < 2; ++a_)
#pragma unroll
    for (int b_ = 0; b_ < 2; ++b_)
      acc[a_][b_] = f32x4{0.f, 0.f, 0.f, 0.f};

  const int ct = tid & 511;
  const int r = ct >> 2, cc = ct & 3;
  const unsigned short* srow = (tid < 512)
      ? A + (size_t)(bM + r) * MD + cc * 8
      : B + (size_t)(bN + r) * MD + cc * 8;
  unsigned short* sdst3 = (tid < 512) ? &sA[0][0] : &sB[0][0];
  auto stage = [&](int c, int kt) {
    gload_lds16(srow + (kt << 5), (char*)(sdst3 + c * 4096) + ct * 16);
  };

  const int nk = MD >> 5;
  stage(0, 0);
  stage(1, 1);
  asm volatile("s_waitcnt vmcnt(1)" ::: "memory");   // tile 0 landed
  __builtin_amdgcn_s_barrier();

  int cur = 0;
  for (int kt = 0; kt < nk; ++kt) {
    if (kt + 2 < nk) stage(cur == 0 ? 2 : cur - 1, kt + 2);
    bf16x8 af[2], bfr[2];
#pragma unroll
    for (int f = 0; f < 2; ++f)
      af[f] = *(const bf16x8*)&sA[cur][(wm + f * 16 + l15) * 32 + g * 8];
#pragma unroll
    for (int f = 0; f < 2; ++f)
      bfr[f] = *(const bf16x8*)&sB[cur][(wn + f * 16 + l15) * 32 + g * 8];
#pragma unroll
    for (int mf = 0; mf < 2; ++mf)
#pragma unroll
      for (int nf = 0; nf < 2; ++nf)
        acc[mf][nf] = __builtin_amdgcn_mfma_f32_16x16x32_bf16(af[mf], bfr[nf], acc[mf][nf], 0, 0, 0);
    if (kt + 2 < nk)
      asm volatile("s_waitcnt vmcnt(1)" ::: "memory");   // tile kt+1 landed
    else if (kt + 1 < nk)
      asm volatile("s_waitcnt vmcnt(0)" ::: "memory");
    if (kt + 1 < nk) __builtin_amdgcn_s_barrier();
    cur = (cur == 2) ? 0 : cur + 1;
  }

#pragma unroll
  for (int nf = 0; nf < 2; ++nf) {
    const int cch = bN + wn + nf * 16 + l15;
    const float bb = bias[cch];
#pragma unroll
    for (int mf = 0; mf < 2; ++mf)
#pragma unroll
      for (int i = 0; i < 4; ++i) {
        const int t = bM + wm + mf * 16 + (g << 2) + i;
        O[(size_t)t * MD + cch] = acc[mf][nf][i] + bb;
      }
  }
}

// ------- flash attention: swapped 32x32, fixed-shift softmax, k-split ----
// (R6 structure, verified; explicit smem layout per R12 lesson)
__global__ __launch_bounds__(512) void attn_fwd(const unsigned short* __restrict__ Qg,
                                                const unsigned short* __restrict__ Kg,
                                                const unsigned short* __restrict__ Vg,
                                                unsigned short* __restrict__ Xout) {
  // [0,32768) K = [half][2 buf][8192B]; [32768,65536) V = [half][2 buf][8192B]
  __shared__ __align__(16) char smem[65536];
  char* sKc = smem;
  char* sVc = smem + 32768;

  const int tid  = threadIdx.x;
  const int lane = tid & 63;
  const int wave = tid >> 6;           // 0..7
  const int ws   = wave & 3;           // q-subtile
  const int grp  = wave >> 2;          // k-half
  const int l31  = lane & 31;
  const int half = lane >> 5;
  const int bh   = blockIdx.y;
  const int q0w  = (blockIdx.x << 7) + (ws << 5);

  const unsigned short* Qb = Qg + (size_t)bh * (SEQ * HD);
  const char* Kb = (const char*)(Kg + (size_t)bh * (SEQ * HD));
  const char* Vb = (const char*)(Vg + (size_t)bh * (HD * SEQ));

  bf16x8 qf[4];
#pragma unroll
  for (int c = 0; c < 4; ++c)
    qf[c] = *(const bf16x8*)&Qb[(size_t)(q0w + l31) * HD + c * 16 + half * 8];

  f32x16 acc_o[2];
#pragma unroll
  for (int dt = 0; dt < 2; ++dt)
#pragma unroll
    for (int e = 0; e < 16; ++e) acc_o[dt][e] = 0.f;
  float lrow = 0.f;

  auto stage = [&](int c, int kt) {
#pragma unroll
    for (int h = 0; h < 2; ++h) {
      const int p = tid << 4;
      const int row = p >> 7;
      const int lcol = (p ^ ((row & 7) << 4)) & 127;
      const int kbase = (h << 10) + (kt << 6);
      gload_lds16(Kb + (size_t)(kbase + row) * (HD * 2) + lcol,
                  sKc + ((h * 2 + c) << 13) + p);
      gload_lds16(Vb + (size_t)row * (SEQ * 2) + (kbase << 1) + lcol,
                  sVc + ((h * 2 + c) << 13) + p);
    }
  };

  const char* myK = sKc + (grp << 14);
  const char* myV = sVc + (grp << 14);

  stage(0, 0);
  __syncthreads();
  int cur = 0;

  const int NT = SEQ / 2 / 64;   // 16 tiles per half
  for (int kt = 0; kt < NT; ++kt) {
    if (kt + 1 < NT) stage(cur ^ 1, kt + 1);

    f32x16 accs[2];
    __builtin_amdgcn_s_setprio(1);
#pragma unroll
    for (int ks = 0; ks < 2; ++ks) {
#pragma unroll
      for (int e = 0; e < 16; ++e) accs[ks][e] = 0.f;
      const int krow = ks * 32 + l31;
      const int swz  = (krow & 7) << 4;
#pragma unroll
      for (int c = 0; c < 4; ++c) {
        const int off = (krow << 7) + ((c * 32 + half * 16) ^ swz);
        bf16x8 kf = *(const bf16x8*)(myK + ((cur) << 13) + off);
        accs[ks] = __builtin_amdgcn_mfma_f32_32x32x16_bf16(kf, qf[c], accs[ks], 0, 0, 0);
      }
    }
    __builtin_amdgcn_s_setprio(0);

    float rsum = 0.f;
#pragma unroll
    for (int ks = 0; ks < 2; ++ks)
#pragma unroll
      for (int e = 0; e < 16; ++e) {
        const float pv = __builtin_amdgcn_exp2f(accs[ks][e]);
        accs[ks][e] = pv;
        rsum += pv;
      }
    lrow += rsum;

    bf16x8 pa[4];
#pragma unroll
    for (int ks = 0; ks < 2; ++ks)
#pragma unroll
      for (int hc = 0; hc < 2; ++hc) {
        const int b = hc * 8;
        unsigned X  = cvtpk(accs[ks][b + 0], accs[ks][b + 1]);
        unsigned X2 = cvtpk(accs[ks][b + 2], accs[ks][b + 3]);
        unsigned Y  = cvtpk(accs[ks][b + 4], accs[ks][b + 5]);
        unsigned Y2 = cvtpk(accs[ks][b + 6], accs[ks][b + 7]);
        plswap(X, Y);
        plswap(X2, Y2);
        union { unsigned u[4]; bf16x8 v; } w;
        w.u[0] = X; w.u[1] = X2; w.u[2] = Y; w.u[3] = Y2;
        pa[ks * 2 + hc] = w.v;
      }

    __builtin_amdgcn_s_setprio(1);
#pragma unroll
    for (int dt = 0; dt < 2; ++dt) {
      const int drow = dt * 32 + l31;
      const int swz  = (drow & 7) << 4;
#pragma unroll
      for (int kc = 0; kc < 4; ++kc) {
        const int off = (drow << 7) + ((kc * 32 + half * 16) ^ swz);
        bf16x8 vf = *(const bf16x8*)(myV + ((cur) << 13) + off);
        acc_o[dt] = __builtin_amdgcn_mfma_f32_32x32x16_bf16(vf, pa[kc], acc_o[dt], 0, 0, 0);
      }
    }
    __builtin_amdgcn_s_setprio(0);

    __syncthreads();
    cur ^= 1;
  }

  // ---- k-half combine via LDS (aliases smem front; 35328B < 65536B) ----
  float lt = lrow + __shfl_xor(lrow, 32);   // this half's full row sum
  float* dump  = (float*)smem;              // [ws][32 q][68 d] fp32 (pad 68)
  float* ldump = dump + 4 * 32 * 68;
  const int base = (ws * 32 + l31) * 68;

  if (grp == 1) {
#pragma unroll
    for (int dt = 0; dt < 2; ++dt)
#pragma unroll
      for (int r4 = 0; r4 < 4; ++r4) {
        const int d0 = dt * 32 + r4 * 8 + half * 4;
        const int e = r4 * 4;
        *(float2*)&dump[base + d0]     = float2{acc_o[dt][e + 0], acc_o[dt][e + 1]};
        *(float2*)&dump[base + d0 + 2] = float2{acc_o[dt][e + 2], acc_o[dt][e + 3]};
      }
    if (half == 0) ldump[ws * 32 + l31] = lt;
  }
  __syncthreads();
  if (grp == 0) {
    const float ltot = lt + ldump[ws * 32 + l31];
    const float inv = 1.f / ltot;
    const int b = bh >> 4, h = bh & 15;
    const int s = q0w + l31;
    const int t = s * NBATCH + b;
    unsigned short* Ot = Xout + (size_t)t * MD + (h << 6);
#pragma unroll
    for (int dt = 0; dt < 2; ++dt)
#pragma unroll
      for (int r4 = 0; r4 < 4; ++r4) {
        const int d0 = dt * 32 + r4 * 8 + half * 4;
        const int e = r4 * 4;
        float2 a0 = *(float2*)&dump[base + d0];
        float2 a1 = *(float2*)&dump[base + d0 + 2];
        uint2 w;
        w.x = cvtpk((acc_o[dt][e + 0] + a0.x) * inv, (acc_o[dt][e + 1] + a0.y) * inv);
        w.y = cvtpk((acc_o[dt][e + 2] + a1.x) * inv, (acc_o[dt][e + 3] + a1.y) * inv);
        *(uint2*)(Ot + d0) = w;
      }
  }
}

extern "C" void kernel_launch(void* const* d_in, const int* in_sizes, int n_in,
                              void* d_out, int out_size, void* d_ws, size_t ws_size,
                              hipStream_t stream) {
  const float* query = (const float*)d_in[0];
  const float* key   = (const float*)d_in[1];
  const float* value = (const float*)d_in[2];
  // d_in[3] = mask: dead code in reference
  const float* Wq = (const float*)d_in[4];
  const float* bq = (const float*)d_in[5];
  const float* Wk = (const float*)d_in[6];
  const float* bk = (const float*)d_in[7];
  const float* Wv = (const float*)d_in[8];
  const float* bv = (const float*)d_in[9];
  const float* Wo = (const float*)d_in[10];
  const float* bo = (const float*)d_in[11];

  char* ws = (char*)d_ws;
  const size_t MB = 1024 * 1024;
  unsigned short* Xa  = (unsigned short*)(ws + 0 * MB);   // attn out [TOK,MD] bf16
  unsigned short* Wqb = (unsigned short*)(ws + 24 * MB);
  unsigned short* Wkb = (unsigned short*)(ws + 26 * MB);
  unsigned short* Wvb = (unsigned short*)(ws + 28 * MB);
  unsigned short* Wob = (unsigned short*)(ws + 30 * MB);
  unsigned short* Qb  = (unsigned short*)(ws + 32 * MB);  // [B,H,S,D]
  unsigned short* Kb  = (unsigned short*)(ws + 40 * MB);  // [B,H,S,D]
  unsigned short* Vb  = (unsigned short*)(ws + 48 * MB);  // [B,H,D,S]

  cvt_w<<<4 * WN8 / 256, 256, 0, stream>>>(Wq, Wk, Wv, Wo, Wqb, Wkb, Wvb, Wob);

  const float kQScale = 0.125f * 1.44269504088896340736f;  // (1/sqrt(64))*log2(e)
  dim3 gQKV(MD / 128, TOK / 128, 3);   // (8, 32, 3) = 768 blocks
  gemm_qkv<<<gQKV, 512, 0, stream>>>(query, key, value, Wqb, Wkb, Wvb,
                                     bq, bk, bv, Qb, Kb, Vb, kQScale);

  dim3 gA(SEQ / 128, NBATCH * NHEAD);  // (16, 32) = 512 blocks, 8 waves each
  attn_fwd<<<gA, 512, 0, stream>>>(Qb, Kb, Vb, Xa);

  dim3 gO(MD / 128, TOK / 128);        // (8, 32) = 256 blocks, 16 waves each
  gemm_oproj<<<gO, 1024, 0, stream>>>(Xa, Wob, bo, (float*)d_out);
  (void)in_sizes; (void)n_in; (void)out_size; (void)ws_size;
}

// Round 18
// 107.433 us; speedup vs baseline: 1.0418x; 1.0046x over previous
//
#include <hip/hip_runtime.h>

#define SEQ    2048
#define NBATCH 2
#define NHEAD  16
#define HD     64
#define MD     1024
#define TOK    (SEQ * NBATCH)   // 4096
#define WN8    (MD * MD / 8)    // 131072 = 2^17

typedef __attribute__((ext_vector_type(4)))  float f32x4;
typedef __attribute__((ext_vector_type(16))) float f32x16;
typedef __attribute__((ext_vector_type(8)))  short bf16x8;
typedef __attribute__((ext_vector_type(8)))  unsigned short u16x8;

__device__ __forceinline__ unsigned short f2bf(float f) {
  union { float f; unsigned int u; } x; x.f = f;
  unsigned int u = x.u + 0x7fffu + ((x.u >> 16) & 1u);   // RNE; inputs are finite
  return (unsigned short)(u >> 16);
}

// v_cvt_pk_bf16_f32: D[15:0]=bf16(lo), D[31:16]=bf16(hi)  (no builtin on gfx950)
__device__ __forceinline__ unsigned cvtpk(float lo, float hi) {
  unsigned r;
  asm("v_cvt_pk_bf16_f32 %0, %1, %2" : "=v"(r) : "v"(lo), "v"(hi));
  return r;
}
// v_permlane32_swap_b32: a' = (a_lo | b_lo), b' = (a_hi | b_hi)
__device__ __forceinline__ void plswap(unsigned &a, unsigned &b) {
  asm volatile("v_permlane32_swap_b32 %0, %1" : "+v"(a), "+v"(b));
}

__device__ __forceinline__ void gload_lds16(const void* g, void* l) {
  typedef const __attribute__((address_space(1))) unsigned int* gp_t;
  typedef __attribute__((address_space(3))) unsigned int* lp_t;
  __builtin_amdgcn_global_load_lds((gp_t)g, (lp_t)l, 16, 0, 0);
}

// -------- fp32 -> bf16 convert, weights only (X is fused into gemm_qkv) ---
__global__ __launch_bounds__(256) void cvt_w(
    const float* __restrict__ wq, const float* __restrict__ wk,
    const float* __restrict__ wv, const float* __restrict__ wo,
    unsigned short* __restrict__ owq, unsigned short* __restrict__ owk,
    unsigned short* __restrict__ owv, unsigned short* __restrict__ owo) {
  const int i = blockIdx.x * 256 + threadIdx.x;
  const int s = i >> 17;           // WN8 = 2^17; boundaries 256-aligned
  const int r = i & (WN8 - 1);
  const float* src = s == 0 ? wq : (s == 1 ? wk : (s == 2 ? wv : wo));
  unsigned short* dst = s == 0 ? owq : (s == 1 ? owk : (s == 2 ? owv : owo));
  const float4* p = (const float4*)src + (size_t)r * 2;
  float4 a = p[0];
  float4 b = p[1];
  u16x8 o;
  o[0] = f2bf(a.x); o[1] = f2bf(a.y); o[2] = f2bf(a.z); o[3] = f2bf(a.w);
  o[4] = f2bf(b.x); o[5] = f2bf(b.y); o[6] = f2bf(b.z); o[7] = f2bf(b.w);
  *((u16x8*)dst + r) = o;
}

// ---- fused cvt+QKV projection, R18: 2-buffer LDS (32KB -> 3 blocks/CU,
// single-pass 768-block grid, no half-occupancy tail). m97-class 2-phase
// loop: stage t+1 during compute t; vmcnt(1)->xwrite; vmcnt(0) drain +
// barrier. X read fp32 from ORIGINAL inputs, cvt_pk in-register. T1
// bijective XCD swizzle.
__global__ __launch_bounds__(512) void gemm_qkv(
    const float* __restrict__ Xq, const float* __restrict__ Xk,
    const float* __restrict__ Xv, const unsigned short* __restrict__ Wq,
    const unsigned short* __restrict__ Wk, const unsigned short* __restrict__ Wv,
    const float* __restrict__ bq, const float* __restrict__ bk, const float* __restrict__ bv,
    unsigned short* __restrict__ Qo, unsigned short* __restrict__ Ko,
    unsigned short* __restrict__ Vo, float qscale) {
  __shared__ unsigned short sA[2][128 * 32];   // M-side
  __shared__ unsigned short sB[2][128 * 32];   // N-side
  const int tid  = threadIdx.x;
  const int lane = tid & 63;
  const int wave = tid >> 6;            // 0..7
  const int wm   = (wave >> 2) << 6;    // 2 M-waves x 64
  const int wn   = (wave & 3) << 5;     // 4 N-waves x 32
  const int l15  = lane & 15;
  const int g    = lane >> 4;

  // T1 swizzle decode: flat = x + 8y + 256z; f(x,gr)=64*(gr>>3)+8x+(gr&7),
  // gr = y + 32z. All 8 x-blocks of a group share flat%8 -> one XCD.
  const int flat = blockIdx.x + (blockIdx.y << 3) + (blockIdx.z << 8);
  const int nx   = (flat & 63) >> 3;               // N-tile 0..7
  const int gr   = ((flat >> 6) << 3) + (flat & 7);// group 0..95
  const int ny   = gr & 31;                        // M-tile 0..31
  const int z    = gr >> 5;                        // 0..2

  const float* Xf; const unsigned short* Wb; const float* bias;
  if (z == 0)      { Xf = Xq; Wb = Wq; bias = bq; }
  else if (z == 1) { Xf = Xk; Wb = Wk; bias = bk; }
  else             { Xf = Xv; Wb = Wv; bias = bv; }
  int bM, bN;
  if (z < 2) { bM = ny << 7; bN = nx << 7; }
  else       { bM = nx << 7; bN = ny << 7; }
  const int bX = (z < 2) ? bM : bN;     // X (token) side base row
  const int bW = (z < 2) ? bN : bM;     // W (channel) side base row
  unsigned short* sX2 = (z < 2) ? &sA[0][0] : &sB[0][0];
  unsigned short* sW2 = (z < 2) ? &sB[0][0] : &sA[0][0];

  f32x4 acc[4][2];
#pragma unroll
  for (int a_ = 0; a_ < 4; ++a_)
#pragma unroll
    for (int b_ = 0; b_ < 2; ++b_)
      acc[a_][b_] = f32x4{0.f, 0.f, 0.f, 0.f};

  const int r = tid >> 2, cc = tid & 3;
  const float* xsrc = Xf + (size_t)(bX + r) * MD + cc * 8;
  const unsigned short* wsrc = Wb + (size_t)(bW + r) * MD + cc * 8;

  float4 ra, rb;                         // single in-flight X reg set
  auto xissue = [&](int kt) {
    ra = *(const float4*)(xsrc + (kt << 5));
    rb = *(const float4*)(xsrc + (kt << 5) + 4);
  };
  auto xwrite = [&](int c) {
    union { unsigned u[4]; bf16x8 v; } w;
    w.u[0] = cvtpk(ra.x, ra.y); w.u[1] = cvtpk(ra.z, ra.w);
    w.u[2] = cvtpk(rb.x, rb.y); w.u[3] = cvtpk(rb.z, rb.w);
    *(bf16x8*)(sX2 + c * 4096 + tid * 8) = w.v;
  };
  auto wissue = [&](int c, int kt) {
    gload_lds16(wsrc + (kt << 5), (char*)(sW2 + c * 4096) + tid * 16);
  };

  auto mfma_step = [&](int c) {
    bf16x8 af[4], bfr[2];
#pragma unroll
    for (int f = 0; f < 4; ++f)
      af[f] = *(const bf16x8*)&sA[c][(wm + f * 16 + l15) * 32 + g * 8];
#pragma unroll
    for (int f = 0; f < 2; ++f)
      bfr[f] = *(const bf16x8*)&sB[c][(wn + f * 16 + l15) * 32 + g * 8];
#pragma unroll
    for (int mf = 0; mf < 4; ++mf)
#pragma unroll
      for (int nf = 0; nf < 2; ++nf)
        acc[mf][nf] = __builtin_amdgcn_mfma_f32_16x16x32_bf16(af[mf], bfr[nf], acc[mf][nf], 0, 0, 0);
  };

  const int nk = MD >> 5;               // 32
  // prologue: tile 0 fully staged before first compute
  xissue(0);                            // 2 loads
  wissue(0, 0);                         // 1 load
  asm volatile("s_waitcnt vmcnt(1)" ::: "memory");   // X(0) regs landed
  xwrite(0);
  asm volatile("s_waitcnt vmcnt(0)" ::: "memory");   // W(0) landed
  asm volatile("s_waitcnt lgkmcnt(0)" ::: "memory");
  __builtin_amdgcn_s_barrier();

  for (int kt = 0; kt < nk; ++kt) {
    if (kt + 1 < nk) { xissue(kt + 1); wissue((kt + 1) & 1, kt + 1); }
    mfma_step(kt & 1);
    if (kt + 1 < nk) {
      asm volatile("s_waitcnt vmcnt(1)" ::: "memory");  // X(kt+1) regs landed
      xwrite((kt + 1) & 1);
      asm volatile("s_waitcnt vmcnt(0)" ::: "memory");  // W(kt+1) landed
      asm volatile("s_waitcnt lgkmcnt(0)" ::: "memory");
      __builtin_amdgcn_s_barrier();
    }
  }

  if (z < 2) {
    unsigned short* O = (z == 0) ? Qo : Ko;
    const float scale = (z == 0) ? qscale : 1.0f;
#pragma unroll
    for (int nf = 0; nf < 2; ++nf) {
      const int cch = bN + wn + nf * 16 + l15;
      const float bb = bias[cch];
      const int h = cch >> 6, d = cch & 63;
#pragma unroll
      for (int mf = 0; mf < 4; ++mf)
#pragma unroll
        for (int i = 0; i < 4; ++i) {
          const int t = bM + wm + mf * 16 + (g << 2) + i;
          const int b = t & 1, s = t >> 1;
          O[((((b << 4) + h) * SEQ + s) << 6) + d] = f2bf((acc[mf][nf][i] + bb) * scale);
        }
    }
  } else {
#pragma unroll
    for (int mf = 0; mf < 4; ++mf)
#pragma unroll
      for (int i = 0; i < 4; ++i) {
        const int rch = bM + wm + mf * 16 + (g << 2) + i;
        const float bb = bias[rch];
        const int h = rch >> 6, d = rch & 63;
#pragma unroll
        for (int nf = 0; nf < 2; ++nf) {
          const int t = bN + wn + nf * 16 + l15;
          const int b = t & 1, s = t >> 1;
          Vo[((((b << 4) + h) << 6) + d) * SEQ + s] = f2bf(acc[mf][nf][i] + bb);
        }
      }
  }
}

// -------- O projection: fp32 out, 16 waves, counted-vmcnt + T1 swizzle ----
// (R14, verified)
__global__ __launch_bounds__(1024) void gemm_oproj(const unsigned short* __restrict__ A,
                                                   const unsigned short* __restrict__ B,
                                                   const float* __restrict__ bias,
                                                   float* __restrict__ O) {
  __shared__ unsigned short sA[3][128 * 32];
  __shared__ unsigned short sB[3][128 * 32];
  const int tid  = threadIdx.x;
  const int lane = tid & 63;
  const int wave = tid >> 6;            // 0..15
  const int wm   = (wave >> 2) << 5;    // 4 M-waves x 32
  const int wn   = (wave & 3) << 5;     // 4 N-waves x 32
  const int l15  = lane & 15;
  const int g    = lane >> 4;

  // T1 swizzle: 8 N-blocks sharing an A panel -> same XCD (gr = y, 0..31)
  const int flat = blockIdx.x + (blockIdx.y << 3);   // 0..255
  const int nx   = (flat & 63) >> 3;
  const int gr   = ((flat >> 6) << 3) + (flat & 7);  // 0..31
  const int bM   = gr << 7;
  const int bN   = nx << 7;

  f32x4 acc[2][2];
#pragma unroll
  for (int a_ = 0; a_ < 2; ++a_)
#pragma unroll
    for (int b_ = 0; b_ < 2; ++b_)
      acc[a_][b_] = f32x4{0.f, 0.f, 0.f, 0.f};

  const int ct = tid & 511;
  const int r = ct >> 2, cc = ct & 3;
  const unsigned short* srow = (tid < 512)
      ? A + (size_t)(bM + r) * MD + cc * 8
      : B + (size_t)(bN + r) * MD + cc * 8;
  unsigned short* sdst3 = (tid < 512) ? &sA[0][0] : &sB[0][0];
  auto stage = [&](int c, int kt) {
    gload_lds16(srow + (kt << 5), (char*)(sdst3 + c * 4096) + ct * 16);
  };

  const int nk = MD >> 5;
  stage(0, 0);
  stage(1, 1);
  asm volatile("s_waitcnt vmcnt(1)" ::: "memory");   // tile 0 landed
  __builtin_amdgcn_s_barrier();

  int cur = 0;
  for (int kt = 0; kt < nk; ++kt) {
    if (kt + 2 < nk) stage(cur == 0 ? 2 : cur - 1, kt + 2);
    bf16x8 af[2], bfr[2];
#pragma unroll
    for (int f = 0; f < 2; ++f)
      af[f] = *(const bf16x8*)&sA[cur][(wm + f * 16 + l15) * 32 + g * 8];
#pragma unroll
    for (int f = 0; f < 2; ++f)
      bfr[f] = *(const bf16x8*)&sB[cur][(wn + f * 16 + l15) * 32 + g * 8];
#pragma unroll
    for (int mf = 0; mf < 2; ++mf)
#pragma unroll
      for (int nf = 0; nf < 2; ++nf)
        acc[mf][nf] = __builtin_amdgcn_mfma_f32_16x16x32_bf16(af[mf], bfr[nf], acc[mf][nf], 0, 0, 0);
    if (kt + 2 < nk)
      asm volatile("s_waitcnt vmcnt(1)" ::: "memory");   // tile kt+1 landed
    else if (kt + 1 < nk)
      asm volatile("s_waitcnt vmcnt(0)" ::: "memory");
    if (kt + 1 < nk) __builtin_amdgcn_s_barrier();
    cur = (cur == 2) ? 0 : cur + 1;
  }

#pragma unroll
  for (int nf = 0; nf < 2; ++nf) {
    const int cch = bN + wn + nf * 16 + l15;
    const float bb = bias[cch];
#pragma unroll
    for (int mf = 0; mf < 2; ++mf)
#pragma unroll
      for (int i = 0; i < 4; ++i) {
        const int t = bM + wm + mf * 16 + (g << 2) + i;
        O[(size_t)t * MD + cch] = acc[mf][nf][i] + bb;
      }
  }
}

// ------- flash attention: swapped 32x32, fixed-shift softmax, k-split ----
// (R6 structure, verified; explicit smem layout per R12 lesson)
__global__ __launch_bounds__(512) void attn_fwd(const unsigned short* __restrict__ Qg,
                                                const unsigned short* __restrict__ Kg,
                                                const unsigned short* __restrict__ Vg,
                                                unsigned short* __restrict__ Xout) {
  // [0,32768) K = [half][2 buf][8192B]; [32768,65536) V = [half][2 buf][8192B]
  __shared__ __align__(16) char smem[65536];
  char* sKc = smem;
  char* sVc = smem + 32768;

  const int tid  = threadIdx.x;
  const int lane = tid & 63;
  const int wave = tid >> 6;           // 0..7
  const int ws   = wave & 3;           // q-subtile
  const int grp  = wave >> 2;          // k-half
  const int l31  = lane & 31;
  const int half = lane >> 5;
  const int bh   = blockIdx.y;
  const int q0w  = (blockIdx.x << 7) + (ws << 5);

  const unsigned short* Qb = Qg + (size_t)bh * (SEQ * HD);
  const char* Kb = (const char*)(Kg + (size_t)bh * (SEQ * HD));
  const char* Vb = (const char*)(Vg + (size_t)bh * (HD * SEQ));

  bf16x8 qf[4];
#pragma unroll
  for (int c = 0; c < 4; ++c)
    qf[c] = *(const bf16x8*)&Qb[(size_t)(q0w + l31) * HD + c * 16 + half * 8];

  f32x16 acc_o[2];
#pragma unroll
  for (int dt = 0; dt < 2; ++dt)
#pragma unroll
    for (int e = 0; e < 16; ++e) acc_o[dt][e] = 0.f;
  float lrow = 0.f;

  auto stage = [&](int c, int kt) {
#pragma unroll
    for (int h = 0; h < 2; ++h) {
      const int p = tid << 4;
      const int row = p >> 7;
      const int lcol = (p ^ ((row & 7) << 4)) & 127;
      const int kbase = (h << 10) + (kt << 6);
      gload_lds16(Kb + (size_t)(kbase + row) * (HD * 2) + lcol,
                  sKc + ((h * 2 + c) << 13) + p);
      gload_lds16(Vb + (size_t)row * (SEQ * 2) + (kbase << 1) + lcol,
                  sVc + ((h * 2 + c) << 13) + p);
    }
  };

  const char* myK = sKc + (grp << 14);
  const char* myV = sVc + (grp << 14);

  stage(0, 0);
  __syncthreads();
  int cur = 0;

  const int NT = SEQ / 2 / 64;   // 16 tiles per half
  for (int kt = 0; kt < NT; ++kt) {
    if (kt + 1 < NT) stage(cur ^ 1, kt + 1);

    f32x16 accs[2];
    __builtin_amdgcn_s_setprio(1);
#pragma unroll
    for (int ks = 0; ks < 2; ++ks) {
#pragma unroll
      for (int e = 0; e < 16; ++e) accs[ks][e] = 0.f;
      const int krow = ks * 32 + l31;
      const int swz  = (krow & 7) << 4;
#pragma unroll
      for (int c = 0; c < 4; ++c) {
        const int off = (krow << 7) + ((c * 32 + half * 16) ^ swz);
        bf16x8 kf = *(const bf16x8*)(myK + ((cur) << 13) + off);
        accs[ks] = __builtin_amdgcn_mfma_f32_32x32x16_bf16(kf, qf[c], accs[ks], 0, 0, 0);
      }
    }
    __builtin_amdgcn_s_setprio(0);

    float rsum = 0.f;
#pragma unroll
    for (int ks = 0; ks < 2; ++ks)
#pragma unroll
      for (int e = 0; e < 16; ++e) {
        const float pv = __builtin_amdgcn_exp2f(accs[ks][e]);
        accs[ks][e] = pv;
        rsum += pv;
      }
    lrow += rsum;

    bf16x8 pa[4];
#pragma unroll
    for (int ks = 0; ks < 2; ++ks)
#pragma unroll
      for (int hc = 0; hc < 2; ++hc) {
        const int b = hc * 8;
        unsigned X  = cvtpk(accs[ks][b + 0], accs[ks][b + 1]);
        unsigned X2 = cvtpk(accs[ks][b + 2], accs[ks][b + 3]);
        unsigned Y  = cvtpk(accs[ks][b + 4], accs[ks][b + 5]);
        unsigned Y2 = cvtpk(accs[ks][b + 6], accs[ks][b + 7]);
        plswap(X, Y);
        plswap(X2, Y2);
        union { unsigned u[4]; bf16x8 v; } w;
        w.u[0] = X; w.u[1] = X2; w.u[2] = Y; w.u[3] = Y2;
        pa[ks * 2 + hc] = w.v;
      }

    __builtin_amdgcn_s_setprio(1);
#pragma unroll
    for (int dt = 0; dt < 2; ++dt) {
      const int drow = dt * 32 + l31;
      const int swz  = (drow & 7) << 4;
#pragma unroll
      for (int kc = 0; kc < 4; ++kc) {
        const int off = (drow << 7) + ((kc * 32 + half * 16) ^ swz);
        bf16x8 vf = *(const bf16x8*)(myV + ((cur) << 13) + off);
        acc_o[dt] = __builtin_amdgcn_mfma_f32_32x32x16_bf16(vf, pa[kc], acc_o[dt], 0, 0, 0);
      }
    }
    __builtin_amdgcn_s_setprio(0);

    __syncthreads();
    cur ^= 1;
  }

  // ---- k-half combine via LDS (aliases smem front; 35328B < 65536B) ----
  float lt = lrow + __shfl_xor(lrow, 32);   // this half's full row sum
  float* dump  = (float*)smem;              // [ws][32 q][68 d] fp32 (pad 68)
  float* ldump = dump + 4 * 32 * 68;
  const int base = (ws * 32 + l31) * 68;

  if (grp == 1) {
#pragma unroll
    for (int dt = 0; dt < 2; ++dt)
#pragma unroll
      for (int r4 = 0; r4 < 4; ++r4) {
        const int d0 = dt * 32 + r4 * 8 + half * 4;
        const int e = r4 * 4;
        *(float2*)&dump[base + d0]     = float2{acc_o[dt][e + 0], acc_o[dt][e + 1]};
        *(float2*)&dump[base + d0 + 2] = float2{acc_o[dt][e + 2], acc_o[dt][e + 3]};
      }
    if (half == 0) ldump[ws * 32 + l31] = lt;
  }
  __syncthreads();
  if (grp == 0) {
    const float ltot = lt + ldump[ws * 32 + l31];
    const float inv = 1.f / ltot;
    const int b = bh >> 4, h = bh & 15;
    const int s = q0w + l31;
    const int t = s * NBATCH + b;
    unsigned short* Ot = Xout + (size_t)t * MD + (h << 6);
#pragma unroll
    for (int dt = 0; dt < 2; ++dt)
#pragma unroll
      for (int r4 = 0; r4 < 4; ++r4) {
        const int d0 = dt * 32 + r4 * 8 + half * 4;
        const int e = r4 * 4;
        float2 a0 = *(float2*)&dump[base + d0];
        float2 a1 = *(float2*)&dump[base + d0 + 2];
        uint2 w;
        w.x = cvtpk((acc_o[dt][e + 0] + a0.x) * inv, (acc_o[dt][e + 1] + a0.y) * inv);
        w.y = cvtpk((acc_o[dt][e + 2] + a1.x) * inv, (acc_o[dt][e + 3] + a1.y) * inv);
        *(uint2*)(Ot + d0) = w;
      }
  }
}

extern "C" void kernel_launch(void* const* d_in, const int* in_sizes, int n_in,
                              void* d_out, int out_size, void* d_ws, size_t ws_size,
                              hipStream_t stream) {
  const float* query = (const float*)d_in[0];
  const float* key   = (const float*)d_in[1];
  const float* value = (const float*)d_in[2];
  // d_in[3] = mask: dead code in reference
  const float* Wq = (const float*)d_in[4];
  const float* bq = (const float*)d_in[5];
  const float* Wk = (const float*)d_in[6];
  const float* bk = (const float*)d_in[7];
  const float* Wv = (const float*)d_in[8];
  const float* bv = (const float*)d_in[9];
  const float* Wo = (const float*)d_in[10];
  const float* bo = (const float*)d_in[11];

  char* ws = (char*)d_ws;
  const size_t MB = 1024 * 1024;
  unsigned short* Xa  = (unsigned short*)(ws + 0 * MB);   // attn out [TOK,MD] bf16
  unsigned short* Wqb = (unsigned short*)(ws + 24 * MB);
  unsigned short* Wkb = (unsigned short*)(ws + 26 * MB);
  unsigned short* Wvb = (unsigned short*)(ws + 28 * MB);
  unsigned short* Wob = (unsigned short*)(ws + 30 * MB);
  unsigned short* Qb  = (unsigned short*)(ws + 32 * MB);  // [B,H,S,D]
  unsigned short* Kb  = (unsigned short*)(ws + 40 * MB);  // [B,H,S,D]
  unsigned short* Vb  = (unsigned short*)(ws + 48 * MB);  // [B,H,D,S]

  cvt_w<<<4 * WN8 / 256, 256, 0, stream>>>(Wq, Wk, Wv, Wo, Wqb, Wkb, Wvb, Wob);

  const float kQScale = 0.125f * 1.44269504088896340736f;  // (1/sqrt(64))*log2(e)
  dim3 gQKV(MD / 128, TOK / 128, 3);   // (8, 32, 3) = 768 blocks
  gemm_qkv<<<gQKV, 512, 0, stream>>>(query, key, value, Wqb, Wkb, Wvb,
                                     bq, bk, bv, Qb, Kb, Vb, kQScale);

  dim3 gA(SEQ / 128, NBATCH * NHEAD);  // (16, 32) = 512 blocks, 8 waves each
  attn_fwd<<<gA, 512, 0, stream>>>(Qb, Kb, Vb, Xa);

  dim3 gO(MD / 128, TOK / 128);        // (8, 32) = 256 blocks, 16 waves each
  gemm_oproj<<<gO, 1024, 0, stream>>>(Xa, Wob, bo, (float*)d_out);
  (void)in_sizes; (void)n_in; (void)out_size; (void)ws_size;
}